// Round 3
// baseline (19864.217 us; speedup 1.0000x reference)
//
#include <hip/hip_runtime.h>

// ---------------------------------------------------------------------------
// 2-layer LSTM (B=4096, H=512, T=100) + per-step FC(63), fp16 MFMA.
// Grid: 32 teams (128 batch rows each) x 8 blocks (64 hidden units each).
// Weights pre-swizzled into MFMA fragment order, loaded straight to regs,
// kept L2-resident by marking all streaming traffic (A tiles, x0, h, out)
// non-temporal. B ring depth 4. A staged in double-buffered LDS (2x64KB),
// XOR-swizzled, with lgkmcnt-only barriers (no vmcnt drain in the pipeline).
// ---------------------------------------------------------------------------

#define HIDN  512
#define SEQL  100
#define BATCH 4096
#define NB    8      // blocks per team
#define BR    128    // batch rows per team

typedef _Float16 f16;
typedef _Float16 half8 __attribute__((ext_vector_type(8)));
typedef float    f32x4 __attribute__((ext_vector_type(4)));
typedef unsigned int u32x4 __attribute__((ext_vector_type(4)));

// ws layout (bytes)
#define OFF_XCAT   0ul                                   // 256*4096*4
#define OFF_X0F    (OFF_XCAT + 256ul*4096*4)             // 2048*4096*4 (frag layout)
#define OFF_BF0    (OFF_X0F  + 2048ul*4096*4)            // 2048*512*2 (frag layout)
#define OFF_BF1I   (OFF_BF0  + 2048ul*512*2)
#define OFF_BF1H   (OFF_BF1I + 2048ul*512*2)
#define OFF_FCF    (OFF_BF1H + 2048ul*512*2)             // 64*512*2
#define OFF_B1P    (OFF_FCF  + 64ul*512*2)               // 2048*4
#define OFF_H0     (OFF_B1P  + 2048ul*4)                 // 2*4096*512*2
#define OFF_H1     (OFF_H0   + 2ul*4096*512*2)
#define OFF_FLAGS  (OFF_H1   + 2ul*4096*512*2)           // 32*128*4
#define FLAG_BYTES (32ul*128*4)

// packed row pr = j*256 + g*64 + u  ->  original gate row g*512 + j*64 + u
__device__ __forceinline__ int orow(int pr){
  return (((pr>>6)&3)<<9) | ((pr>>8)<<6) | (pr&63);
}
__device__ __forceinline__ float sigm(float x){ return 1.f/(1.f + __expf(-x)); }
__device__ __forceinline__ float tanhx(float x){ return 1.f - 2.f/(1.f + __expf(2.f*x)); }
__device__ __forceinline__ f32x4 splat4(float v){ f32x4 r; r[0]=v; r[1]=v; r[2]=v; r[3]=v; return r; }

// lgkmcnt-only barrier: orders LDS ops without draining vmcnt (keeps global
// prefetches in flight across the barrier).
#define LBAR() do { asm volatile("s_waitcnt lgkmcnt(0)" ::: "memory"); \
                    __builtin_amdgcn_s_barrier(); } while(0)

// ---------------- prep 1: xcatT[c][b], c in [0,256) (254 real) ----------------
__global__ __launch_bounds__(256) void k_xcat(
    const int* __restrict__ sl, const int* __restrict__ el,
    const float* __restrict__ sc, const float* __restrict__ ec,
    const float* __restrict__ emb, float* __restrict__ xcatT)
{
  int b = blockIdx.x*256 + threadIdx.x;
  int c = blockIdx.y;
  float v = 0.f;
  if      (c < 64 ) v = emb[sl[b]*64 + c];
  else if (c < 128) v = emb[el[b]*64 + (c-64)];
  else if (c < 191) v = sc[b*63 + (c-128)];
  else if (c < 254) v = ec[b*63 + (c-191)];
  xcatT[c*4096 + b] = v;
}

// ---------------- prep 2: weights -> fp16 MFMA fragment layout ----------------
// BF[m] fragment (j,g,wc,kc): f16 idx = (((j*4+g)*4+wc)*16 + kc)*512 + lane*8+e
//   value = W[g*512 + j*64 + wc*16 + (lane&15)][kc*32 + (lane>>4)*8 + e]
// fcF fragment (wc,kc): idx = ((wc*16+kc)*512 + lane*8+e), col = wc*16+(lane&15)
__global__ __launch_bounds__(256) void k_pack(
    const float* __restrict__ Whh0, const float* __restrict__ Wih1,
    const float* __restrict__ Whh1, const float* __restrict__ fcW,
    const float* __restrict__ bih1, const float* __restrict__ bhh1,
    f16* __restrict__ BF0, f16* __restrict__ BF1i, f16* __restrict__ BF1h,
    f16* __restrict__ fcF, float* __restrict__ b1p)
{
  int bx = blockIdx.x, t = threadIdx.x;
  if (bx < 384){
    int m   = bx / 128;           // 0:Whh0 1:Wih1 2:Whh1
    int rem = bx % 128;           // j*16 + g*4 + wc
    int jj = rem >> 4, g = (rem >> 2) & 3, wc = rem & 3;
    const float* src = (m==0) ? Whh0 : (m==1) ? Wih1 : Whh1;
    f16* dst = (m==0) ? BF0 : (m==1) ? BF1i : BF1h;
    size_t fb = (size_t)(((jj*4+g)*4+wc)*16) * 512;
    for (int s=0; s<4; s++){
      int pid = t + s*256;        // (kc, lane)
      int kc = pid >> 6, lane = pid & 63;
      int lcc = lane & 15, qd = lane >> 4;
      int orig = g*512 + jj*64 + wc*16 + lcc;
      const float* sp = src + (size_t)orig*512 + kc*32 + qd*8;
      f16* d = dst + fb + (size_t)kc*512 + lane*8;
#pragma unroll
      for (int e=0; e<8; e++) d[e] = (f16)sp[e];
    }
  } else if (bx < 388){
    int wc = bx - 384;
    for (int s=0; s<4; s++){
      int pid = t + s*256;
      int kc = pid >> 6, lane = pid & 63;
      int lcc = lane & 15, qd = lane >> 4;
      int col = wc*16 + lcc;
      f16* d = fcF + (size_t)(wc*16 + kc)*512 + lane*8;
      if (col < 63){
        const float* sp = fcW + (size_t)col*512 + kc*32 + qd*8;
#pragma unroll
        for (int e=0; e<8; e++) d[e] = (f16)sp[e];
      } else {
#pragma unroll
        for (int e=0; e<8; e++) d[e] = (f16)0.f;
      }
    }
  } else {
    int jj = bx - 388;
    int orig = (((t>>6)&3)<<9) | (jj<<6) | (t&63);
    b1p[jj*256 + t] = bih1[orig] + bhh1[orig];
  }
}

// ---------------- prep 3: x0 = x @ W_ih0^T + b_ih0 + b_hh0, fragment layout --
// x0F strides (f32): team 262144, j 32768, g 8192, wr 4096, mt 1024, wc 256,
//                    lane 4, r 1
__global__ __launch_bounds__(256) void k_x0(
    const float* __restrict__ xcatT, const float* __restrict__ Wih0,
    const float* __restrict__ bih0, const float* __restrict__ bhh0,
    float* __restrict__ x0F)
{
  int pr0 = blockIdx.x * 16;
  int b   = blockIdx.y * 256 + threadIdx.x;
  float a[16];
#pragma unroll
  for (int i=0;i<16;i++) a[i] = 0.f;
  for (int k=0;k<254;k++){
    float xv = xcatT[k*4096 + b];
#pragma unroll
    for (int i=0;i<16;i++)
      a[i] = fmaf(xv, Wih0[orow(pr0+i)*254 + k], a[i]);   // uniform addr -> s_load
  }
  int team = b>>7, wrr = (b>>6)&1, mtt = (b>>4)&3, qd = (b>>2)&3, r = b&3;
#pragma unroll
  for (int i=0;i<16;i++){
    int pr = pr0 + i;
    int orig = orow(pr);
    int jj = pr>>8, g = (pr>>6)&3, u = pr&63, wcc = u>>4, lcc = u&15;
    size_t idx = (size_t)team*262144 + (size_t)jj*32768 + g*8192 + wrr*4096
               + mtt*1024 + wcc*256 + (qd*16 + lcc)*4 + r;
    x0F[idx] = a[i] + bih0[orig] + bhh0[orig];
  }
}

// ---------------- main persistent LSTM kernel --------------------------------
__global__ __launch_bounds__(512, 1) void k_lstm(
    const float* __restrict__ x0F, const f16* __restrict__ BF0,
    const f16* __restrict__ BF1i, const f16* __restrict__ BF1h,
    const f16* __restrict__ fcF, const float* __restrict__ b1p,
    const float* __restrict__ fcb, f16* __restrict__ h0buf,
    f16* __restrict__ h1buf, unsigned int* __restrict__ flags,
    float* __restrict__ out)
{
  __shared__ f16 Ash[2][128*256];   // 2 x 64 KB half-K A tiles, XOR-swizzled

  const int tid  = threadIdx.x;
  const int blk  = blockIdx.x;
  const int j    = blk & 7;        // hidden slice (== XCD with %8 round robin)
  const int team = blk >> 3;       // batch tile
  const int b0   = team * BR;
  const int w = tid >> 6, wr = w >> 2, wc = w & 3;
  const int lane = tid & 63, quad = lane >> 4, lc = lane & 15;
  const int ucol = wc*16 + lc;                 // unit within slice [0,64)
  const bool des = (j == (team & 7));          // designated fc block of team

  // B fragment bases: one pointer per matrix; g stride 32768, kc stride 512
  const size_t fboff = (size_t)(((j*4)*4+wc)*16)*512 + lane*8;
  const f16* Bb0  = BF0  + fboff;
  const f16* Bb1i = BF1i + fboff;
  const f16* Bb1h = BF1h + fboff;
  const f16* fcp = fcF + (size_t)(wc*16)*512 + lane*8;
  const float* x0p = x0F + (size_t)team*262144 + (size_t)j*32768
                   + wr*4096 + wc*256 + lane*4;

  float b1v[4];
#pragma unroll
  for (int g=0; g<4; g++) b1v[g] = b1p[j*256 + g*64 + ucol];
  const float fcbv = (ucol < 63) ? fcb[ucol] : 0.f;

  f32x4 c0[4], c1[4];
#pragma unroll
  for (int mt=0; mt<4; mt++){ c0[mt] = splat4(0.f); c1[mt] = splat4(0.f); }

  // staging / swizzle helpers
  const int srow  = tid >> 2;              // 0..127
  const int sslot = tid & 3;               // 16B-slot group
  const int swzb  = (quad*16) ^ ((lc&3)<<4);
  const int swzf  = (lc&4)<<4;

  unsigned int* tflags = flags + team*128;
  auto barrier = [&](int idx){
    __syncthreads();
    if (tid == 0){
      __threadfence();
      __hip_atomic_fetch_add(&tflags[idx], 1u, __ATOMIC_RELAXED, __HIP_MEMORY_SCOPE_AGENT);
      while (__hip_atomic_load(&tflags[idx], __ATOMIC_RELAXED, __HIP_MEMORY_SCOPE_AGENT) < (unsigned)NB)
        __builtin_amdgcn_s_sleep(4);
      __threadfence();
    }
    __syncthreads();
  };

  // load one 128x256 f16 half-tile into regs (non-temporal: zero-reuse stream)
  auto LD8 = [&](const f16* src, u32x4 (&v)[8]){
#pragma unroll
    for (int i=0;i<8;i++)
      v[i] = __builtin_nontemporal_load(
               (const u32x4*)(src + (size_t)srow*HIDN + (sslot + i*4)*8));
  };
  // store regs into Ash[buf], XOR-swizzled
  auto ST8 = [&](int buf, const u32x4 (&v)[8]){
#pragma unroll
    for (int i=0;i<8;i++){
      int cb = ((sslot + i*4)*16) ^ ((srow&7)<<4);
      *(u32x4*)((char*)Ash[buf] + srow*512 + cb) = v[i];
    }
  };

  // one full K=512 GEMM pass: acc[g][mt] += A(128x512) * B(512x256)
  auto PASS = [&](const f16* src, const f16* Bb, bool dofc,
                  f32x4 (&acc)[4][4], f32x4* fca){
    // B ring, depth 4 (L2-hit latency cover ~4 kq iterations)
    half8 br[4][4]; half8 fr[4];
#pragma unroll
    for (int d=0; d<4; d++){
#pragma unroll
      for (int g=0; g<4; g++)
        br[d][g] = *(const half8*)(Bb + (size_t)g*32768 + d*512);
      if (dofc) fr[d] = *(const half8*)(fcp + d*512);
    }
    u32x4 sva[8], svb[8];
    LD8(src, sva);
    ST8(0, sva);
    LD8(src + 256, svb);       // half-1 global loads in flight across LBAR
    LBAR();                    // buf0 ready
#pragma unroll
    for (int kh=0; kh<2; kh++){
      char* Ab = (char*)Ash[kh] + (wr*64 + lc)*512 + swzb;
      half8 aC[4];
#pragma unroll
      for (int mt=0; mt<4; mt++)
        aC[mt] = *(const half8*)(Ab + mt*8192 + swzf);
#pragma unroll
      for (int kq=0; kq<8; kq++){
        const int kc = kh*8 + kq;
        half8 aN[4];
        if (kq < 7){
          const int colx = ((kq+1)*64) ^ swzf;
#pragma unroll
          for (int mt=0; mt<4; mt++)
            aN[mt] = *(const half8*)(Ab + mt*8192 + colx);
        }
        if (kh == 0 && kq == 2) ST8(1, svb);   // overlap dbuf write w/ compute
        // consume ring slot kc&3
#pragma unroll
        for (int g=0; g<4; g++)
#pragma unroll
          for (int mt=0; mt<4; mt++)
            acc[g][mt] = __builtin_amdgcn_mfma_f32_16x16x32_f16(aC[mt], br[kc&3][g], acc[g][mt], 0, 0, 0);
        if (dofc)
#pragma unroll
          for (int mt=0; mt<4; mt++)
            fca[mt] = __builtin_amdgcn_mfma_f32_16x16x32_f16(aC[mt], fr[kc&3], fca[mt], 0, 0, 0);
        // refill ring slot with kc+4 (after consumption)
        if (kc + 4 < 16){
#pragma unroll
          for (int g=0; g<4; g++)
            br[kc&3][g] = *(const half8*)(Bb + (size_t)g*32768 + (kc+4)*512);
          if (dofc) fr[kc&3] = *(const half8*)(fcp + (kc+4)*512);
        }
        if (kq < 7){
#pragma unroll
          for (int mt=0; mt<4; mt++) aC[mt] = aN[mt];
        }
      }
      if (kh == 0) LBAR();     // buf1 ready; buf0 reads done
    }
  };

  for (int t=0; t<SEQL; t++){
    const int p  = t & 1;
    const int pp = (t-1) & 1;
    f16* h0wr = h0buf + (size_t)p*BATCH*HIDN;
    f16* h1wr = h1buf + (size_t)p*BATCH*HIDN;

    // ----- layer 0: pre0 = x0 + h0(t-1) @ Whh0^T -----
    f32x4 acc[4][4];
#pragma unroll
    for (int g=0; g<4; g++)
#pragma unroll
      for (int mt=0; mt<4; mt++)
        acc[g][mt] = __builtin_nontemporal_load(
                       (const f32x4*)(x0p + g*8192 + mt*1024));
    if (t > 0){
      PASS(h0buf + (size_t)pp*BATCH*HIDN + (size_t)b0*HIDN, Bb0, false, acc, nullptr);
    }
#pragma unroll
    for (int mt=0; mt<4; mt++){
#pragma unroll
      for (int r=0; r<4; r++){
        float iv = sigm(acc[0][mt][r]);
        float fv = sigm(acc[1][mt][r]);
        float gv = tanhx(acc[2][mt][r]);
        float ov = sigm(acc[3][mt][r]);
        float cn = fv*c0[mt][r] + iv*gv;
        c0[mt][r] = cn;
        float hn = ov * tanhx(cn);
        int row = wr*64 + mt*16 + quad*4 + r;
        __builtin_nontemporal_store((f16)hn,
            &h0wr[(size_t)(b0+row)*HIDN + j*64 + ucol]);
      }
    }
    barrier(t);

    // ----- layer 1: pre1 = b1 + h0(t) @ Wih1^T + h1(t-1) @ Whh1^T (+ fc y(t-1)) -----
#pragma unroll
    for (int g=0; g<4; g++)
#pragma unroll
      for (int mt=0; mt<4; mt++)
        acc[g][mt] = splat4(b1v[g]);
    f32x4 fca[4];
#pragma unroll
    for (int mt=0; mt<4; mt++) fca[mt] = splat4(fcbv);

    PASS(h0buf + (size_t)p*BATCH*HIDN + (size_t)b0*HIDN, Bb1i, false, acc, nullptr);
    if (t > 0){
      PASS(h1buf + (size_t)pp*BATCH*HIDN + (size_t)b0*HIDN, Bb1h, des, acc, fca);
      if (des && ucol < 63){
#pragma unroll
        for (int mt=0; mt<4; mt++)
#pragma unroll
          for (int r=0; r<4; r++){
            int row = wr*64 + mt*16 + quad*4 + r;
            __builtin_nontemporal_store(fca[mt][r],
                &out[((b0+row)*63 + ucol)*100 + (t-1)]);
          }
      }
    }
#pragma unroll
    for (int mt=0; mt<4; mt++){
#pragma unroll
      for (int r=0; r<4; r++){
        float iv = sigm(acc[0][mt][r]);
        float fv = sigm(acc[1][mt][r]);
        float gv = tanhx(acc[2][mt][r]);
        float ov = sigm(acc[3][mt][r]);
        float cn = fv*c1[mt][r] + iv*gv;
        c1[mt][r] = cn;
        float hn = ov * tanhx(cn);
        int row = wr*64 + mt*16 + quad*4 + r;
        __builtin_nontemporal_store((f16)hn,
            &h1wr[(size_t)(b0+row)*HIDN + j*64 + ucol]);
      }
    }
  }

  // ----- epilogue: y(99) from h1(99) (parity 1), designated block only -----
  barrier(SEQL);
  if (des){
    const f16* h1last = h1buf + (size_t)1*BATCH*HIDN + (size_t)b0*HIDN;
    f32x4 fca[4];
#pragma unroll
    for (int mt=0; mt<4; mt++) fca[mt] = splat4(fcbv);
    u32x4 sv[8];
#pragma unroll
    for (int kh=0; kh<2; kh++){
      LD8(h1last + kh*256, sv);
      ST8(0, sv);
      __syncthreads();
#pragma unroll
      for (int kq=0; kq<8; kq++){
        int kc = kh*8 + kq;
        half8 af[4];
        const int colx = (kq*64) ^ swzf;
        char* Ab = (char*)Ash[0] + (wr*64 + lc)*512 + swzb;
#pragma unroll
        for (int mt=0; mt<4; mt++)
          af[mt] = *(const half8*)(Ab + mt*8192 + colx);
        half8 fb = *(const half8*)(fcp + (size_t)kc*512);
#pragma unroll
        for (int mt=0; mt<4; mt++)
          fca[mt] = __builtin_amdgcn_mfma_f32_16x16x32_f16(af[mt], fb, fca[mt], 0, 0, 0);
      }
      __syncthreads();
    }
    if (ucol < 63){
#pragma unroll
      for (int mt=0; mt<4; mt++)
#pragma unroll
        for (int r=0; r<4; r++){
          int row = wr*64 + mt*16 + quad*4 + r;
          __builtin_nontemporal_store(fca[mt][r],
              &out[((b0+row)*63 + ucol)*100 + 99]);
        }
    }
  }
}

// ---------------------------------------------------------------------------
extern "C" void kernel_launch(void* const* d_in, const int* in_sizes, int n_in,
                              void* d_out, int out_size, void* d_ws, size_t ws_size,
                              hipStream_t stream)
{
  const int*   sl   = (const int*)  d_in[0];
  const int*   el   = (const int*)  d_in[1];
  const float* sc   = (const float*)d_in[2];
  const float* ec   = (const float*)d_in[3];
  const float* emb  = (const float*)d_in[4];
  const float* Wih0 = (const float*)d_in[5];
  const float* Whh0 = (const float*)d_in[6];
  const float* bih0 = (const float*)d_in[7];
  const float* bhh0 = (const float*)d_in[8];
  const float* Wih1 = (const float*)d_in[9];
  const float* Whh1 = (const float*)d_in[10];
  const float* bih1 = (const float*)d_in[11];
  const float* bhh1 = (const float*)d_in[12];
  const float* fcW  = (const float*)d_in[13];
  const float* fcb  = (const float*)d_in[14];

  char* ws = (char*)d_ws;
  float* xcatT = (float*)(ws + OFF_XCAT);
  float* x0F   = (float*)(ws + OFF_X0F);
  f16*   BF0   = (f16*)  (ws + OFF_BF0);
  f16*   BF1i  = (f16*)  (ws + OFF_BF1I);
  f16*   BF1h  = (f16*)  (ws + OFF_BF1H);
  f16*   fcF   = (f16*)  (ws + OFF_FCF);
  float* b1p   = (float*)(ws + OFF_B1P);
  f16*   h0b   = (f16*)  (ws + OFF_H0);
  f16*   h1b   = (f16*)  (ws + OFF_H1);
  unsigned int* flags = (unsigned int*)(ws + OFF_FLAGS);

  hipMemsetAsync(flags, 0, FLAG_BYTES, stream);
  k_xcat<<<dim3(16, 256), 256, 0, stream>>>(sl, el, sc, ec, emb, xcatT);
  k_pack<<<396, 256, 0, stream>>>(Whh0, Wih1, Whh1, fcW, bih1, bhh1,
                                  BF0, BF1i, BF1h, fcF, b1p);
  k_x0<<<dim3(128, 16), 256, 0, stream>>>(xcatT, Wih0, bih0, bhh0, x0F);
  k_lstm<<<256, 512, 0, stream>>>(x0F, BF0, BF1i, BF1h, fcF, b1p, fcb,
                                  h0b, h1b, flags, (float*)d_out);
}

// Round 4
// 10453.627 us; speedup vs baseline: 1.9002x; 1.9002x over previous
//
#include <hip/hip_runtime.h>

// ---------------------------------------------------------------------------
// 2-layer LSTM (B=4096, H=512, T=100) + per-step FC(63), fp16 MFMA.
// Grid: 32 teams (128 batch rows each) x 8 blocks (64 hidden units each).
// A (h state) and B (weights) staged through double-buffered XOR-swizzled
// LDS in K=64 chunks (conflict-free ds_read_b128 / ds_write_b128).
// All intra-GEMM barriers are lgkmcnt-only so reg-staged global prefetches
// stay in flight across barriers (no vmcnt drain in the pipeline).
// B loads are block-wide contiguous -> L2-resident (empirically verified by
// the original LDS-staged kernel: 8.5 GB total fetch).
// ---------------------------------------------------------------------------

#define HIDN  512
#define SEQL  100
#define BATCH 4096
#define NB    8      // blocks per team
#define BR    128    // batch rows per team

typedef _Float16 f16;
typedef _Float16 half8 __attribute__((ext_vector_type(8)));
typedef float    f32x4 __attribute__((ext_vector_type(4)));
typedef unsigned int u32x4 __attribute__((ext_vector_type(4)));

// ws layout (bytes)
#define OFF_XCAT   0ul                                   // 256*4096*4
#define OFF_X0F    (OFF_XCAT + 256ul*4096*4)             // 2048*4096*4 (frag layout)
#define OFF_WP0    (OFF_X0F  + 2048ul*4096*4)            // 2048*512*2 (row-packed)
#define OFF_WP1I   (OFF_WP0  + 2048ul*512*2)
#define OFF_WP1H   (OFF_WP1I + 2048ul*512*2)
#define OFF_FCF    (OFF_WP1H + 2048ul*512*2)             // 64*512*2 (frag layout)
#define OFF_B1P    (OFF_FCF  + 64ul*512*2)               // 2048*4
#define OFF_H0     (OFF_B1P  + 2048ul*4)                 // 2*4096*512*2
#define OFF_H1     (OFF_H0   + 2ul*4096*512*2)
#define OFF_FLAGS  (OFF_H1   + 2ul*4096*512*2)           // 32*128*4
#define FLAG_BYTES (32ul*128*4)

// packed row pr = j*256 + g*64 + u  ->  original gate row g*512 + j*64 + u
__device__ __forceinline__ int orow(int pr){
  return (((pr>>6)&3)<<9) | ((pr>>8)<<6) | (pr&63);
}
__device__ __forceinline__ float sigm(float x){ return 1.f/(1.f + __expf(-x)); }
__device__ __forceinline__ float tanhx(float x){ return 1.f - 2.f/(1.f + __expf(2.f*x)); }
__device__ __forceinline__ f32x4 splat4(float v){ f32x4 r; r[0]=v; r[1]=v; r[2]=v; r[3]=v; return r; }

// lgkmcnt-only barrier: orders LDS ops without draining vmcnt (keeps global
// prefetches in flight across the barrier).
#define LBAR() do { asm volatile("s_waitcnt lgkmcnt(0)" ::: "memory"); \
                    __builtin_amdgcn_s_barrier(); } while(0)

// ---------------- prep 1: xcatT[c][b], c in [0,256) (254 real) ----------------
__global__ __launch_bounds__(256) void k_xcat(
    const int* __restrict__ sl, const int* __restrict__ el,
    const float* __restrict__ sc, const float* __restrict__ ec,
    const float* __restrict__ emb, float* __restrict__ xcatT)
{
  int b = blockIdx.x*256 + threadIdx.x;
  int c = blockIdx.y;
  float v = 0.f;
  if      (c < 64 ) v = emb[sl[b]*64 + c];
  else if (c < 128) v = emb[el[b]*64 + (c-64)];
  else if (c < 191) v = sc[b*63 + (c-128)];
  else if (c < 254) v = ec[b*63 + (c-191)];
  xcatT[c*4096 + b] = v;
}

// ---------------- prep 2: pack weights (row-packed fp16), fcF frags, biases --
__global__ __launch_bounds__(256) void k_pack(
    const float* __restrict__ Whh0, const float* __restrict__ Wih1,
    const float* __restrict__ Whh1, const float* __restrict__ fcW,
    const float* __restrict__ bih1, const float* __restrict__ bhh1,
    f16* __restrict__ Wp0, f16* __restrict__ Wp1i, f16* __restrict__ Wp1h,
    f16* __restrict__ fcF, float* __restrict__ b1p)
{
  int bx = blockIdx.x, t = threadIdx.x;
  if (bx < 6144){
    int m  = bx >> 11;            // 0:Whh0 1:Wih1 2:Whh1
    int pr = bx & 2047;
    const float* src = (m==0) ? Whh0 : (m==1) ? Wih1 : Whh1;
    f16* dst = (m==0) ? Wp0 : (m==1) ? Wp1i : Wp1h;
    int orig = orow(pr);
    dst[(size_t)pr*512 + t      ] = (f16)src[(size_t)orig*512 + t      ];
    dst[(size_t)pr*512 + t + 256] = (f16)src[(size_t)orig*512 + t + 256];
  } else if (bx < 6148){
    // fcF fragment (wc,kc): idx = ((wc*16+kc)*512 + lane*8+e), col=wc*16+(lane&15)
    int wc = bx - 6144;
    for (int s=0; s<4; s++){
      int pid = t + s*256;
      int kc = pid >> 6, lane = pid & 63;
      int lcc = lane & 15, qd = lane >> 4;
      int col = wc*16 + lcc;
      f16* d = fcF + (size_t)(wc*16 + kc)*512 + lane*8;
      if (col < 63){
        const float* sp = fcW + (size_t)col*512 + kc*32 + qd*8;
#pragma unroll
        for (int e=0; e<8; e++) d[e] = (f16)sp[e];
      } else {
#pragma unroll
        for (int e=0; e<8; e++) d[e] = (f16)0.f;
      }
    }
  } else {
    int jj = bx - 6148;
    int orig = (((t>>6)&3)<<9) | (jj<<6) | (t&63);
    b1p[jj*256 + t] = bih1[orig] + bhh1[orig];
  }
}

// ---------------- prep 3: x0 = x @ W_ih0^T + b_ih0 + b_hh0, fragment layout --
// x0F strides (f32): team 262144, j 32768, g 8192, wr 4096, mt 1024, wc 256,
//                    lane 4, r 1
__global__ __launch_bounds__(256) void k_x0(
    const float* __restrict__ xcatT, const float* __restrict__ Wih0,
    const float* __restrict__ bih0, const float* __restrict__ bhh0,
    float* __restrict__ x0F)
{
  int pr0 = blockIdx.x * 16;
  int b   = blockIdx.y * 256 + threadIdx.x;
  float a[16];
#pragma unroll
  for (int i=0;i<16;i++) a[i] = 0.f;
  for (int k=0;k<254;k++){
    float xv = xcatT[k*4096 + b];
#pragma unroll
    for (int i=0;i<16;i++)
      a[i] = fmaf(xv, Wih0[orow(pr0+i)*254 + k], a[i]);   // uniform addr -> s_load
  }
  int team = b>>7, wrr = (b>>6)&1, mtt = (b>>4)&3, qd = (b>>2)&3, r = b&3;
#pragma unroll
  for (int i=0;i<16;i++){
    int pr = pr0 + i;
    int orig = orow(pr);
    int jj = pr>>8, g = (pr>>6)&3, u = pr&63, wcc = u>>4, lcc = u&15;
    size_t idx = (size_t)team*262144 + (size_t)jj*32768 + g*8192 + wrr*4096
               + mtt*1024 + wcc*256 + (qd*16 + lcc)*4 + r;
    x0F[idx] = a[i] + bih0[orig] + bhh0[orig];
  }
}

// ---------------- main persistent LSTM kernel --------------------------------
__global__ __launch_bounds__(512, 1) void k_lstm(
    const float* __restrict__ x0F, const f16* __restrict__ Wp0,
    const f16* __restrict__ Wp1i, const f16* __restrict__ Wp1h,
    const f16* __restrict__ fcF, const float* __restrict__ b1p,
    const float* __restrict__ fcb, f16* __restrict__ h0buf,
    f16* __restrict__ h1buf, unsigned int* __restrict__ flags,
    float* __restrict__ out)
{
  __shared__ f16 Ash[2][128*64];   // 2 x 16 KB A chunk (128 rows x 64 k)
  __shared__ f16 Bsh[2][256*64];   // 2 x 32 KB B chunk (256 gate-rows x 64 k)

  const int tid  = threadIdx.x;
  const int blk  = blockIdx.x;
  const int j    = blk & 7;        // hidden slice (== XCD with %8 round robin)
  const int team = blk >> 3;       // batch tile
  const int b0   = team * BR;
  const int w = tid >> 6, wr = w >> 2, wc = w & 3;
  const int lane = tid & 63, quad = lane >> 4, lc = lane & 15;
  const int ucol = wc*16 + lc;                 // unit within slice [0,64)
  const bool des = (j == (team & 7));          // designated fc block of team

  const f16* Wb0  = Wp0  + (size_t)(j*256)*512;
  const f16* Wb1i = Wp1i + (size_t)(j*256)*512;
  const f16* Wb1h = Wp1h + (size_t)(j*256)*512;
  const f16* fcp  = fcF + (size_t)(wc*16)*512 + lane*8;
  const float* x0p = x0F + (size_t)team*262144 + (size_t)j*32768
                   + wr*4096 + wc*256 + lane*4;

  float b1v[4];
#pragma unroll
  for (int g=0; g<4; g++) b1v[g] = b1p[j*256 + g*64 + ucol];
  const float fcbv = (ucol < 63) ? fcb[ucol] : 0.f;

  f32x4 c0[4], c1[4];
#pragma unroll
  for (int mt=0; mt<4; mt++){ c0[mt] = splat4(0.f); c1[mt] = splat4(0.f); }

  unsigned int* tflags = flags + team*128;
  auto barrier = [&](int idx){
    __syncthreads();
    if (tid == 0){
      __threadfence();
      __hip_atomic_fetch_add(&tflags[idx], 1u, __ATOMIC_RELAXED, __HIP_MEMORY_SCOPE_AGENT);
      while (__hip_atomic_load(&tflags[idx], __ATOMIC_RELAXED, __HIP_MEMORY_SCOPE_AGENT) < (unsigned)NB)
        __builtin_amdgcn_s_sleep(4);
      __threadfence();
    }
    __syncthreads();
  };

  // staging geometry: thread -> row ra, slot pair {s0, s0+4}; slot = 16B unit
  const int ra = tid >> 2, s0 = tid & 3;
  const int sw0 = ((s0    ) ^ (ra & 7)) * 16;   // swizzled byte offset in row
  const int sw1 = ((s0 + 4) ^ (ra & 7)) * 16;
  const int rsw = lc & 7;                        // read-side row swizzle key

  // compute one K=64 chunk from buf: acc[g][mt] += A*B (+ optional fc)
  auto CHUNK = [&](int buf, int kc, bool dofc, int fck0,
                   f32x4 (&acc)[4][4], f32x4* fca){
    const char* Ab = (const char*)Ash[buf];
    const char* Bb = (const char*)Bsh[buf];
#pragma unroll
    for (int kq=0; kq<2; kq++){
      const int sa = ((kq*4 + quad) ^ rsw) * 16;
      half8 af[4], bf[4], fb{};
#pragma unroll
      for (int mt=0; mt<4; mt++)
        af[mt] = *(const half8*)(Ab + (wr*64 + mt*16 + lc)*128 + sa);
#pragma unroll
      for (int g=0; g<4; g++)
        bf[g] = *(const half8*)(Bb + (g*64 + wc*16 + lc)*128 + sa);
      if (dofc)
        fb = *(const half8*)(fcp + (size_t)((kc - fck0)*2 + kq)*512);
      __builtin_amdgcn_s_setprio(1);
#pragma unroll
      for (int g=0; g<4; g++)
#pragma unroll
        for (int mt=0; mt<4; mt++)
          acc[g][mt] = __builtin_amdgcn_mfma_f32_16x16x32_f16(af[mt], bf[g], acc[g][mt], 0, 0, 0);
      if (dofc)
#pragma unroll
        for (int mt=0; mt<4; mt++)
          fca[mt] = __builtin_amdgcn_mfma_f32_16x16x32_f16(af[mt], fb, fca[mt], 0, 0, 0);
      __builtin_amdgcn_s_setprio(0);
    }
  };

  // GEMM pass over nch K=64 chunks; dbuf LDS, lgkmcnt-only barriers,
  // reg-staged global prefetch 1 chunk ahead (in flight across LBAR).
  auto PASS = [&](int nch, auto&& Aat, auto&& Bat, bool dofc, int fck0,
                  f32x4 (&acc)[4][4], f32x4* fca){
    u32x4 va0, va1, vb0, vb1, vb2, vb3;
    auto LDc = [&](int kc){
      const f16* As = Aat(kc);
      const f16* Bs = Bat(kc);
      va0 = __builtin_nontemporal_load((const u32x4*)(As + (size_t)ra*HIDN + s0*8));
      va1 = __builtin_nontemporal_load((const u32x4*)(As + (size_t)ra*HIDN + s0*8 + 32));
      vb0 = *(const u32x4*)(Bs + (size_t)ra*HIDN + s0*8);
      vb1 = *(const u32x4*)(Bs + (size_t)ra*HIDN + s0*8 + 32);
      vb2 = *(const u32x4*)(Bs + (size_t)(ra+128)*HIDN + s0*8);
      vb3 = *(const u32x4*)(Bs + (size_t)(ra+128)*HIDN + s0*8 + 32);
    };
    auto STc = [&](int buf){
      char* ar  = (char*)Ash[buf] + ra*128;
      char* br0 = (char*)Bsh[buf] + ra*128;
      char* br1 = (char*)Bsh[buf] + (ra+128)*128;
      *(u32x4*)(ar  + sw0) = va0;  *(u32x4*)(ar  + sw1) = va1;
      *(u32x4*)(br0 + sw0) = vb0;  *(u32x4*)(br0 + sw1) = vb1;
      *(u32x4*)(br1 + sw0) = vb2;  *(u32x4*)(br1 + sw1) = vb3;
    };
    LDc(0); STc(0);
    if (nch > 1) LDc(1);
    for (int kc=0; kc<nch; kc++){
      LBAR();                              // buf[kc&1] ready; old reads done
      if (kc+1 < nch) STc((kc+1)&1);       // write next buf (vmcnt wait local)
      if (kc+2 < nch) LDc(kc+2);           // prefetch, stays in flight
      CHUNK(kc&1, kc, dofc && kc >= fck0, fck0, acc, fca);
    }
  };

  for (int t=0; t<SEQL; t++){
    const int p  = t & 1;
    const int pp = (t-1) & 1;
    const f16* h0rd = h0buf + (size_t)pp*BATCH*HIDN + (size_t)b0*HIDN;
    const f16* h1rd = h1buf + (size_t)pp*BATCH*HIDN + (size_t)b0*HIDN;
    f16* h0wr = h0buf + (size_t)p*BATCH*HIDN;
    f16* h1wr = h1buf + (size_t)p*BATCH*HIDN;

    // ----- layer 0: pre0 = x0 + h0(t-1) @ Whh0^T -----
    f32x4 acc[4][4];
#pragma unroll
    for (int g=0; g<4; g++)
#pragma unroll
      for (int mt=0; mt<4; mt++)
        acc[g][mt] = __builtin_nontemporal_load(
                       (const f32x4*)(x0p + g*8192 + mt*1024));
    if (t > 0){
      PASS(8, [&](int kc){ return h0rd + kc*64; },
              [&](int kc){ return Wb0  + kc*64; },
           false, 0, acc, (f32x4*)nullptr);
    }
#pragma unroll
    for (int mt=0; mt<4; mt++){
#pragma unroll
      for (int r=0; r<4; r++){
        float iv = sigm(acc[0][mt][r]);
        float fv = sigm(acc[1][mt][r]);
        float gv = tanhx(acc[2][mt][r]);
        float ov = sigm(acc[3][mt][r]);
        float cn = fv*c0[mt][r] + iv*gv;
        c0[mt][r] = cn;
        float hn = ov * tanhx(cn);
        int row = wr*64 + mt*16 + quad*4 + r;
        h0wr[(size_t)(b0+row)*HIDN + j*64 + ucol] = (f16)hn;
      }
    }
    barrier(t);

    // ----- layer 1: pre1 = b1 + h0(t) @ Wih1^T + h1(t-1) @ Whh1^T (+ fc y(t-1)) -----
    const f16* h0cur = h0buf + (size_t)p*BATCH*HIDN + (size_t)b0*HIDN;
#pragma unroll
    for (int g=0; g<4; g++)
#pragma unroll
      for (int mt=0; mt<4; mt++)
        acc[g][mt] = splat4(b1v[g]);
    f32x4 fca[4];
#pragma unroll
    for (int mt=0; mt<4; mt++) fca[mt] = splat4(fcbv);

    if (t > 0){
      PASS(16, [&](int kc){ return kc < 8 ? h0cur + kc*64 : h1rd  + (kc-8)*64; },
               [&](int kc){ return kc < 8 ? Wb1i  + kc*64 : Wb1h + (kc-8)*64; },
           des, 8, acc, fca);
      if (des && ucol < 63){
#pragma unroll
        for (int mt=0; mt<4; mt++)
#pragma unroll
          for (int r=0; r<4; r++){
            int row = wr*64 + mt*16 + quad*4 + r;
            __builtin_nontemporal_store(fca[mt][r],
                &out[((b0+row)*63 + ucol)*100 + (t-1)]);
          }
      }
    } else {
      PASS(8, [&](int kc){ return h0cur + kc*64; },
              [&](int kc){ return Wb1i  + kc*64; },
           false, 0, acc, (f32x4*)nullptr);
    }
#pragma unroll
    for (int mt=0; mt<4; mt++){
#pragma unroll
      for (int r=0; r<4; r++){
        float iv = sigm(acc[0][mt][r]);
        float fv = sigm(acc[1][mt][r]);
        float gv = tanhx(acc[2][mt][r]);
        float ov = sigm(acc[3][mt][r]);
        float cn = fv*c1[mt][r] + iv*gv;
        c1[mt][r] = cn;
        float hn = ov * tanhx(cn);
        int row = wr*64 + mt*16 + quad*4 + r;
        h1wr[(size_t)(b0+row)*HIDN + j*64 + ucol] = (f16)hn;
      }
    }
  }

  // ----- epilogue: y(99) from h1(99) (parity 1), designated block only -----
  barrier(SEQL);
  if (des){
    const f16* h1last = h1buf + (size_t)1*BATCH*HIDN + (size_t)b0*HIDN;
    f32x4 fca[4];
#pragma unroll
    for (int mt=0; mt<4; mt++) fca[mt] = splat4(fcbv);
    for (int kc=0; kc<8; kc++){
      __syncthreads();
      const f16* As = h1last + kc*64;
      u32x4 a0 = *(const u32x4*)(As + (size_t)ra*HIDN + s0*8);
      u32x4 a1 = *(const u32x4*)(As + (size_t)ra*HIDN + s0*8 + 32);
      char* ar = (char*)Ash[0] + ra*128;
      *(u32x4*)(ar + sw0) = a0;  *(u32x4*)(ar + sw1) = a1;
      __syncthreads();
#pragma unroll
      for (int kq=0; kq<2; kq++){
        const int sa = ((kq*4 + quad) ^ rsw) * 16;
        half8 af[4];
#pragma unroll
        for (int mt=0; mt<4; mt++)
          af[mt] = *(const half8*)((const char*)Ash[0] + (wr*64 + mt*16 + lc)*128 + sa);
        half8 fb = *(const half8*)(fcp + (size_t)(kc*2 + kq)*512);
#pragma unroll
        for (int mt=0; mt<4; mt++)
          fca[mt] = __builtin_amdgcn_mfma_f32_16x16x32_f16(af[mt], fb, fca[mt], 0, 0, 0);
      }
    }
    if (ucol < 63){
#pragma unroll
      for (int mt=0; mt<4; mt++)
#pragma unroll
        for (int r=0; r<4; r++){
          int row = wr*64 + mt*16 + quad*4 + r;
          __builtin_nontemporal_store(fca[mt][r],
              &out[((b0+row)*63 + ucol)*100 + 99]);
        }
    }
  }
}

// ---------------------------------------------------------------------------
extern "C" void kernel_launch(void* const* d_in, const int* in_sizes, int n_in,
                              void* d_out, int out_size, void* d_ws, size_t ws_size,
                              hipStream_t stream)
{
  const int*   sl   = (const int*)  d_in[0];
  const int*   el   = (const int*)  d_in[1];
  const float* sc   = (const float*)d_in[2];
  const float* ec   = (const float*)d_in[3];
  const float* emb  = (const float*)d_in[4];
  const float* Wih0 = (const float*)d_in[5];
  const float* Whh0 = (const float*)d_in[6];
  const float* bih0 = (const float*)d_in[7];
  const float* bhh0 = (const float*)d_in[8];
  const float* Wih1 = (const float*)d_in[9];
  const float* Whh1 = (const float*)d_in[10];
  const float* bih1 = (const float*)d_in[11];
  const float* bhh1 = (const float*)d_in[12];
  const float* fcW  = (const float*)d_in[13];
  const float* fcb  = (const float*)d_in[14];

  char* ws = (char*)d_ws;
  float* xcatT = (float*)(ws + OFF_XCAT);
  float* x0F   = (float*)(ws + OFF_X0F);
  f16*   Wp0   = (f16*)  (ws + OFF_WP0);
  f16*   Wp1i  = (f16*)  (ws + OFF_WP1I);
  f16*   Wp1h  = (f16*)  (ws + OFF_WP1H);
  f16*   fcF   = (f16*)  (ws + OFF_FCF);
  float* b1p   = (float*)(ws + OFF_B1P);
  f16*   h0b   = (f16*)  (ws + OFF_H0);
  f16*   h1b   = (f16*)  (ws + OFF_H1);
  unsigned int* flags = (unsigned int*)(ws + OFF_FLAGS);

  hipMemsetAsync(flags, 0, FLAG_BYTES, stream);
  k_xcat<<<dim3(16, 256), 256, 0, stream>>>(sl, el, sc, ec, emb, xcatT);
  k_pack<<<6156, 256, 0, stream>>>(Whh0, Wih1, Whh1, fcW, bih1, bhh1,
                                   Wp0, Wp1i, Wp1h, fcF, b1p);
  k_x0<<<dim3(128, 16), 256, 0, stream>>>(xcatT, Wih0, bih0, bhh0, x0F);
  k_lstm<<<256, 512, 0, stream>>>(x0F, Wp0, Wp1i, Wp1h, fcF, b1p, fcb,
                                  h0b, h1b, flags, (float*)d_out);
}

// Round 5
// 10439.557 us; speedup vs baseline: 1.9028x; 1.0013x over previous
//
#include <hip/hip_runtime.h>

// ---------------------------------------------------------------------------
// 2-layer LSTM (B=4096, H=512, T=100) + per-step FC(63), fp16 MFMA.
// Grid: 32 teams (128 batch rows each) x 8 blocks (64 hidden units each).
// A (h state) and B (weights) staged through double-buffered XOR-swizzled
// LDS in K=64 chunks. 2-deep register pipeline: chunk k+1's global loads
// issue at k-2 (~2 chunk-times in flight, covers L3 latency of cross-XCD h).
// Pass prologue loads pre-issued across pass/step boundaries (weights before
// the team barrier, h0 across the step boundary). lgkmcnt-only barriers.
// ---------------------------------------------------------------------------

#define HIDN  512
#define SEQL  100
#define BATCH 4096
#define NB    8      // blocks per team
#define BR    128    // batch rows per team

typedef _Float16 f16;
typedef _Float16 half8 __attribute__((ext_vector_type(8)));
typedef float    f32x4 __attribute__((ext_vector_type(4)));
typedef unsigned int u32x4 __attribute__((ext_vector_type(4)));

// ws layout (bytes)
#define OFF_XCAT   0ul                                   // 256*4096*4
#define OFF_X0F    (OFF_XCAT + 256ul*4096*4)             // 2048*4096*4 (frag layout)
#define OFF_WP0    (OFF_X0F  + 2048ul*4096*4)            // 2048*512*2 (row-packed)
#define OFF_WP1I   (OFF_WP0  + 2048ul*512*2)
#define OFF_WP1H   (OFF_WP1I + 2048ul*512*2)
#define OFF_FCF    (OFF_WP1H + 2048ul*512*2)             // 64*512*2 (frag layout)
#define OFF_B1P    (OFF_FCF  + 64ul*512*2)               // 2048*4
#define OFF_H0     (OFF_B1P  + 2048ul*4)                 // 2*4096*512*2
#define OFF_H1     (OFF_H0   + 2ul*4096*512*2)
#define OFF_FLAGS  (OFF_H1   + 2ul*4096*512*2)           // 32*128*4
#define FLAG_BYTES (32ul*128*4)

template<int N> struct IC { static constexpr int v = N; };

// packed row pr = j*256 + g*64 + u  ->  original gate row g*512 + j*64 + u
__device__ __forceinline__ int orow(int pr){
  return (((pr>>6)&3)<<9) | ((pr>>8)<<6) | (pr&63);
}
__device__ __forceinline__ float sigm(float x){ return 1.f/(1.f + __expf(-x)); }
__device__ __forceinline__ float tanhx(float x){ return 1.f - 2.f/(1.f + __expf(2.f*x)); }
__device__ __forceinline__ f32x4 splat4(float v){ f32x4 r; r[0]=v; r[1]=v; r[2]=v; r[3]=v; return r; }

// lgkmcnt-only barrier: orders LDS ops without draining vmcnt (keeps global
// prefetches in flight across the barrier).
#define LBAR() do { asm volatile("s_waitcnt lgkmcnt(0)" ::: "memory"); \
                    __builtin_amdgcn_s_barrier(); } while(0)

// ---------------- prep 1: xcatT[c][b], c in [0,256) (254 real) ----------------
__global__ __launch_bounds__(256) void k_xcat(
    const int* __restrict__ sl, const int* __restrict__ el,
    const float* __restrict__ sc, const float* __restrict__ ec,
    const float* __restrict__ emb, float* __restrict__ xcatT)
{
  int b = blockIdx.x*256 + threadIdx.x;
  int c = blockIdx.y;
  float v = 0.f;
  if      (c < 64 ) v = emb[sl[b]*64 + c];
  else if (c < 128) v = emb[el[b]*64 + (c-64)];
  else if (c < 191) v = sc[b*63 + (c-128)];
  else if (c < 254) v = ec[b*63 + (c-191)];
  xcatT[c*4096 + b] = v;
}

// ---------------- prep 2: pack weights (row-packed fp16), fcF frags, biases --
__global__ __launch_bounds__(256) void k_pack(
    const float* __restrict__ Whh0, const float* __restrict__ Wih1,
    const float* __restrict__ Whh1, const float* __restrict__ fcW,
    const float* __restrict__ bih1, const float* __restrict__ bhh1,
    f16* __restrict__ Wp0, f16* __restrict__ Wp1i, f16* __restrict__ Wp1h,
    f16* __restrict__ fcF, float* __restrict__ b1p)
{
  int bx = blockIdx.x, t = threadIdx.x;
  if (bx < 6144){
    int m  = bx >> 11;            // 0:Whh0 1:Wih1 2:Whh1
    int pr = bx & 2047;
    const float* src = (m==0) ? Whh0 : (m==1) ? Wih1 : Whh1;
    f16* dst = (m==0) ? Wp0 : (m==1) ? Wp1i : Wp1h;
    int orig = orow(pr);
    dst[(size_t)pr*512 + t      ] = (f16)src[(size_t)orig*512 + t      ];
    dst[(size_t)pr*512 + t + 256] = (f16)src[(size_t)orig*512 + t + 256];
  } else if (bx < 6148){
    // fcF fragment (wc,kc): idx = ((wc*16+kc)*512 + lane*8+e), col=wc*16+(lane&15)
    int wc = bx - 6144;
    for (int s=0; s<4; s++){
      int pid = t + s*256;
      int kc = pid >> 6, lane = pid & 63;
      int lcc = lane & 15, qd = lane >> 4;
      int col = wc*16 + lcc;
      f16* d = fcF + (size_t)(wc*16 + kc)*512 + lane*8;
      if (col < 63){
        const float* sp = fcW + (size_t)col*512 + kc*32 + qd*8;
#pragma unroll
        for (int e=0; e<8; e++) d[e] = (f16)sp[e];
      } else {
#pragma unroll
        for (int e=0; e<8; e++) d[e] = (f16)0.f;
      }
    }
  } else {
    int jj = bx - 6148;
    int orig = (((t>>6)&3)<<9) | (jj<<6) | (t&63);
    b1p[jj*256 + t] = bih1[orig] + bhh1[orig];
  }
}

// ---------------- prep 3: x0 = x @ W_ih0^T + b_ih0 + b_hh0, fragment layout --
// x0F strides (f32): team 262144, j 32768, g 8192, wr 4096, mt 1024, wc 256,
//                    lane 4, r 1
__global__ __launch_bounds__(256) void k_x0(
    const float* __restrict__ xcatT, const float* __restrict__ Wih0,
    const float* __restrict__ bih0, const float* __restrict__ bhh0,
    float* __restrict__ x0F)
{
  int pr0 = blockIdx.x * 16;
  int b   = blockIdx.y * 256 + threadIdx.x;
  float a[16];
#pragma unroll
  for (int i=0;i<16;i++) a[i] = 0.f;
  for (int k=0;k<254;k++){
    float xv = xcatT[k*4096 + b];
#pragma unroll
    for (int i=0;i<16;i++)
      a[i] = fmaf(xv, Wih0[orow(pr0+i)*254 + k], a[i]);   // uniform addr -> s_load
  }
  int team = b>>7, wrr = (b>>6)&1, mtt = (b>>4)&3, qd = (b>>2)&3, r = b&3;
#pragma unroll
  for (int i=0;i<16;i++){
    int pr = pr0 + i;
    int orig = orow(pr);
    int jj = pr>>8, g = (pr>>6)&3, u = pr&63, wcc = u>>4, lcc = u&15;
    size_t idx = (size_t)team*262144 + (size_t)jj*32768 + g*8192 + wrr*4096
               + mtt*1024 + wcc*256 + (qd*16 + lcc)*4 + r;
    x0F[idx] = a[i] + bih0[orig] + bhh0[orig];
  }
}

// ---------------- main persistent LSTM kernel --------------------------------
__global__ __launch_bounds__(512, 1) void k_lstm(
    const float* __restrict__ x0F, const f16* __restrict__ Wp0,
    const f16* __restrict__ Wp1i, const f16* __restrict__ Wp1h,
    const f16* __restrict__ fcF, const float* __restrict__ b1p,
    const float* __restrict__ fcb, f16* __restrict__ h0buf,
    f16* __restrict__ h1buf, unsigned int* __restrict__ flags,
    float* __restrict__ out)
{
  __shared__ f16 Ash[2][128*64];   // 2 x 16 KB A chunk (128 rows x 64 k)
  __shared__ f16 Bsh[2][256*64];   // 2 x 32 KB B chunk (256 gate-rows x 64 k)

  const int tid  = threadIdx.x;
  const int blk  = blockIdx.x;
  const int j    = blk & 7;        // hidden slice (== XCD with %8 round robin)
  const int team = blk >> 3;       // batch tile
  const int b0   = team * BR;
  const int w = tid >> 6, wr = w >> 2, wc = w & 3;
  const int lane = tid & 63, quad = lane >> 4, lc = lane & 15;
  const int ucol = wc*16 + lc;                 // unit within slice [0,64)
  const bool des = (j == (team & 7));          // designated fc block of team

  const f16* Wb0  = Wp0  + (size_t)(j*256)*512;
  const f16* Wb1i = Wp1i + (size_t)(j*256)*512;
  const f16* Wb1h = Wp1h + (size_t)(j*256)*512;
  const f16* fcp  = fcF + (size_t)(wc*16)*512 + lane*8;
  const float* x0p = x0F + (size_t)team*262144 + (size_t)j*32768
                   + wr*4096 + wc*256 + lane*4;

  float b1v[4];
#pragma unroll
  for (int g=0; g<4; g++) b1v[g] = b1p[j*256 + g*64 + ucol];
  const float fcbv = (ucol < 63) ? fcb[ucol] : 0.f;

  f32x4 c0[4], c1[4];
#pragma unroll
  for (int mt=0; mt<4; mt++){ c0[mt] = splat4(0.f); c1[mt] = splat4(0.f); }

  unsigned int* tflags = flags + team*128;
  auto barrier = [&](int idx){
    __syncthreads();
    if (tid == 0){
      __threadfence();
      __hip_atomic_fetch_add(&tflags[idx], 1u, __ATOMIC_RELAXED, __HIP_MEMORY_SCOPE_AGENT);
      while (__hip_atomic_load(&tflags[idx], __ATOMIC_RELAXED, __HIP_MEMORY_SCOPE_AGENT) < (unsigned)NB)
        __builtin_amdgcn_s_sleep(4);
      __threadfence();
    }
    __syncthreads();
  };

  // staging geometry: thread -> row ra, slot pair {s0, s0+4}; slot = 16B unit
  const int ra = tid >> 2, s0 = tid & 3;
  const int sw0 = ((s0    ) ^ (ra & 7)) * 16;   // swizzled byte offset in row
  const int sw1 = ((s0 + 4) ^ (ra & 7)) * 16;
  const int rsw = lc & 7;                        // read-side row swizzle key

  // ---- 2-deep register staging: two named sets ----
  u32x4 rA[2][2], rB[2][4];

  auto LD_A = [&](int s, const f16* As){
    rA[s][0] = __builtin_nontemporal_load((const u32x4*)(As + (size_t)ra*HIDN + s0*8));
    rA[s][1] = __builtin_nontemporal_load((const u32x4*)(As + (size_t)ra*HIDN + s0*8 + 32));
  };
  auto LD_B = [&](int s, const f16* Bs){
    rB[s][0] = *(const u32x4*)(Bs + (size_t)ra*HIDN + s0*8);
    rB[s][1] = *(const u32x4*)(Bs + (size_t)ra*HIDN + s0*8 + 32);
    rB[s][2] = *(const u32x4*)(Bs + (size_t)(ra+128)*HIDN + s0*8);
    rB[s][3] = *(const u32x4*)(Bs + (size_t)(ra+128)*HIDN + s0*8 + 32);
  };
  auto STC = [&](int buf, int s){
    char* ar  = (char*)Ash[buf] + ra*128;
    char* br0 = (char*)Bsh[buf] + ra*128;
    char* br1 = (char*)Bsh[buf] + (ra+128)*128;
    *(u32x4*)(ar  + sw0) = rA[s][0];  *(u32x4*)(ar  + sw1) = rA[s][1];
    *(u32x4*)(br0 + sw0) = rB[s][0];  *(u32x4*)(br0 + sw1) = rB[s][1];
    *(u32x4*)(br1 + sw0) = rB[s][2];  *(u32x4*)(br1 + sw1) = rB[s][3];
  };

  f32x4 acc[4][4];
  f32x4 fca[4];

  // compute one K=64 chunk from LDS buf
  auto CHUNK = [&](int buf, int kc, bool dofck){
    const char* Ab = (const char*)Ash[buf];
    const char* Bb = (const char*)Bsh[buf];
#pragma unroll
    for (int kq=0; kq<2; kq++){
      const int sa = ((kq*4 + quad) ^ rsw) * 16;
      half8 af[4], bf[4];
#pragma unroll
      for (int mt=0; mt<4; mt++)
        af[mt] = *(const half8*)(Ab + (wr*64 + mt*16 + lc)*128 + sa);
#pragma unroll
      for (int g=0; g<4; g++)
        bf[g] = *(const half8*)(Bb + (g*64 + wc*16 + lc)*128 + sa);
#pragma unroll
      for (int g=0; g<4; g++)
#pragma unroll
        for (int mt=0; mt<4; mt++)
          acc[g][mt] = __builtin_amdgcn_mfma_f32_16x16x32_f16(af[mt], bf[g], acc[g][mt], 0, 0, 0);
      if (dofck){
        half8 fb = *(const half8*)(fcp + (size_t)(kc*2 + kq)*512);
#pragma unroll
        for (int mt=0; mt<4; mt++)
          fca[mt] = __builtin_amdgcn_mfma_f32_16x16x32_f16(af[mt], fb, fca[mt], 0, 0, 0);
      }
    }
  };

  // GEMM pass over NCH K=64 chunks. pre: 0 = load everything here,
  // 1 = B of chunks 0,1 pre-issued, 2 = A+B of chunks 0,1 pre-issued.
  // fc (dofc) applies to chunks kc<8 (layer1 h1-half).
  auto PASS = [&](auto NC, auto&& Aat, auto&& Bat, bool dofc, int pre){
    constexpr int NCH = decltype(NC)::v;
    if (pre < 2){ LD_A(0, Aat(0)); LD_A(1, Aat(1)); }
    if (pre < 1){ LD_B(0, Bat(0)); LD_B(1, Bat(1)); }
    STC(0, 0);
    LD_A(0, Aat(2)); LD_B(0, Bat(2));
    for (int kc=0; kc<NCH; kc+=2){
      // ---- even chunk kc (reads buf0) ----
      LBAR();
      STC(1, 1);                                 // chunk kc+1
      if (kc+3 < NCH){ LD_A(1, Aat(kc+3)); LD_B(1, Bat(kc+3)); }
      CHUNK(0, kc, dofc && kc < 8);
      // ---- odd chunk kc+1 (reads buf1) ----
      LBAR();
      if (kc+2 < NCH){
        STC(0, 0);                               // chunk kc+2
        if (kc+4 < NCH){ LD_A(0, Aat(kc+4)); LD_B(0, Bat(kc+4)); }
      }
      CHUNK(1, kc+1, dofc && (kc+1) < 8);
    }
  };

  // gate nonlinearity + h store
  auto GATES = [&](f32x4 (&cc)[4], f16* hw){
#pragma unroll
    for (int mt=0; mt<4; mt++){
#pragma unroll
      for (int r=0; r<4; r++){
        float iv = sigm(acc[0][mt][r]);
        float fv = sigm(acc[1][mt][r]);
        float gv = tanhx(acc[2][mt][r]);
        float ov = sigm(acc[3][mt][r]);
        float cn = fv*cc[mt][r] + iv*gv;
        cc[mt][r] = cn;
        float hn = ov * tanhx(cn);
        int row = wr*64 + mt*16 + quad*4 + r;
        hw[(size_t)(b0+row)*HIDN + j*64 + ucol] = (f16)hn;
      }
    }
  };
  auto LOADX0 = [&](){
#pragma unroll
    for (int g=0; g<4; g++)
#pragma unroll
      for (int mt=0; mt<4; mt++)
        acc[g][mt] = __builtin_nontemporal_load(
                       (const f32x4*)(x0p + g*8192 + mt*1024));
  };

  // ================= t = 0 =================
  LOADX0();
  GATES(c0, h0buf);                         // h0(0), parity 0
  barrier(0);
#pragma unroll
  for (int g=0; g<4; g++)
#pragma unroll
    for (int mt=0; mt<4; mt++) acc[g][mt] = splat4(b1v[g]);
  {
    const f16* h0cur = h0buf + (size_t)b0*HIDN;      // parity 0
    PASS(IC<8>{}, [&](int kc){ return h0cur + kc*64; },
                  [&](int kc){ return Wb1i  + kc*64; }, false, 0);
  }
  // tail: pre-issue layer0 of t=1 (h0 parity 0, synced by barrier(0))
  {
    const f16* h0n = h0buf + (size_t)b0*HIDN;
    LD_A(0, h0n); LD_A(1, h0n + 64);
    LD_B(0, Wb0); LD_B(1, Wb0 + 64);
  }
  GATES(c1, h1buf);                         // h1(0), parity 0
  LOADX0();

  // ================= main loop =================
  for (int t=1; t<SEQL; t++){
    const int p  = t & 1;
    const int pp = (t-1) & 1;
    const f16* h0rd  = h0buf + (size_t)pp*BATCH*HIDN + (size_t)b0*HIDN;
    const f16* h1rd  = h1buf + (size_t)pp*BATCH*HIDN + (size_t)b0*HIDN;
    const f16* h0cur = h0buf + (size_t)p*BATCH*HIDN + (size_t)b0*HIDN;
    f16* h0wr = h0buf + (size_t)p*BATCH*HIDN;
    f16* h1wr = h1buf + (size_t)p*BATCH*HIDN;

    // ----- layer 0: pre0 = x0 + h0(t-1) @ Whh0^T  (acc preloaded with x0) -----
    PASS(IC<8>{}, [&](int kc){ return h0rd + kc*64; },
                  [&](int kc){ return Wb0  + kc*64; }, false, 2);
    // pre-issue layer1 weight chunks 0,1 (static -> safe across the barrier)
    LD_B(0, Wb1h); LD_B(1, Wb1h + 64);
    GATES(c0, h0wr);
    barrier(t);

    // ----- layer 1: pre1 = b1 + h1(t-1)@Whh1^T (kc0-7, +fc) + h0(t)@Wih1^T -----
#pragma unroll
    for (int g=0; g<4; g++)
#pragma unroll
      for (int mt=0; mt<4; mt++) acc[g][mt] = splat4(b1v[g]);
#pragma unroll
    for (int mt=0; mt<4; mt++) fca[mt] = splat4(fcbv);

    PASS(IC<16>{},
         [&](int kc){ return kc < 8 ? h1rd + kc*64 : h0cur + (kc-8)*64; },
         [&](int kc){ return kc < 8 ? Wb1h + kc*64 : Wb1i  + (kc-8)*64; },
         des, 1);
    if (des && ucol < 63){
#pragma unroll
      for (int mt=0; mt<4; mt++)
#pragma unroll
        for (int r=0; r<4; r++){
          int row = wr*64 + mt*16 + quad*4 + r;
          __builtin_nontemporal_store(fca[mt][r],
              &out[((b0+row)*63 + ucol)*100 + (t-1)]);
        }
    }
    // tail: pre-issue layer0 of t+1 (h0 parity p, synced by barrier(t))
    if (t < SEQL-1){
      const f16* h0n = h0buf + (size_t)p*BATCH*HIDN + (size_t)b0*HIDN;
      LD_A(0, h0n); LD_A(1, h0n + 64);
      LD_B(0, Wb0); LD_B(1, Wb0 + 64);
    }
    GATES(c1, h1wr);
    if (t < SEQL-1) LOADX0();
  }

  // ----- epilogue: y(99) from h1(99) (parity 1), designated block only -----
  barrier(SEQL);
  if (des){
    const f16* h1last = h1buf + (size_t)1*BATCH*HIDN + (size_t)b0*HIDN;
#pragma unroll
    for (int mt=0; mt<4; mt++) fca[mt] = splat4(fcbv);
    for (int kc=0; kc<8; kc++){
      __syncthreads();
      const f16* As = h1last + kc*64;
      u32x4 a0 = *(const u32x4*)(As + (size_t)ra*HIDN + s0*8);
      u32x4 a1 = *(const u32x4*)(As + (size_t)ra*HIDN + s0*8 + 32);
      char* ar = (char*)Ash[0] + ra*128;
      *(u32x4*)(ar + sw0) = a0;  *(u32x4*)(ar + sw1) = a1;
      __syncthreads();
#pragma unroll
      for (int kq=0; kq<2; kq++){
        const int sa = ((kq*4 + quad) ^ rsw) * 16;
        half8 af[4];
#pragma unroll
        for (int mt=0; mt<4; mt++)
          af[mt] = *(const half8*)((const char*)Ash[0] + (wr*64 + mt*16 + lc)*128 + sa);
        half8 fb = *(const half8*)(fcp + (size_t)(kc*2 + kq)*512);
#pragma unroll
        for (int mt=0; mt<4; mt++)
          fca[mt] = __builtin_amdgcn_mfma_f32_16x16x32_f16(af[mt], fb, fca[mt], 0, 0, 0);
      }
    }
    if (ucol < 63){
#pragma unroll
      for (int mt=0; mt<4; mt++)
#pragma unroll
        for (int r=0; r<4; r++){
          int row = wr*64 + mt*16 + quad*4 + r;
          __builtin_nontemporal_store(fca[mt][r],
              &out[((b0+row)*63 + ucol)*100 + 99]);
        }
    }
  }
}

// ---------------------------------------------------------------------------
extern "C" void kernel_launch(void* const* d_in, const int* in_sizes, int n_in,
                              void* d_out, int out_size, void* d_ws, size_t ws_size,
                              hipStream_t stream)
{
  const int*   sl   = (const int*)  d_in[0];
  const int*   el   = (const int*)  d_in[1];
  const float* sc   = (const float*)d_in[2];
  const float* ec   = (const float*)d_in[3];
  const float* emb  = (const float*)d_in[4];
  const float* Wih0 = (const float*)d_in[5];
  const float* Whh0 = (const float*)d_in[6];
  const float* bih0 = (const float*)d_in[7];
  const float* bhh0 = (const float*)d_in[8];
  const float* Wih1 = (const float*)d_in[9];
  const float* Whh1 = (const float*)d_in[10];
  const float* bih1 = (const float*)d_in[11];
  const float* bhh1 = (const float*)d_in[12];
  const float* fcW  = (const float*)d_in[13];
  const float* fcb  = (const float*)d_in[14];

  char* ws = (char*)d_ws;
  float* xcatT = (float*)(ws + OFF_XCAT);
  float* x0F   = (float*)(ws + OFF_X0F);
  f16*   Wp0   = (f16*)  (ws + OFF_WP0);
  f16*   Wp1i  = (f16*)  (ws + OFF_WP1I);
  f16*   Wp1h  = (f16*)  (ws + OFF_WP1H);
  f16*   fcF   = (f16*)  (ws + OFF_FCF);
  float* b1p   = (float*)(ws + OFF_B1P);
  f16*   h0b   = (f16*)  (ws + OFF_H0);
  f16*   h1b   = (f16*)  (ws + OFF_H1);
  unsigned int* flags = (unsigned int*)(ws + OFF_FLAGS);

  hipMemsetAsync(flags, 0, FLAG_BYTES, stream);
  k_xcat<<<dim3(16, 256), 256, 0, stream>>>(sl, el, sc, ec, emb, xcatT);
  k_pack<<<6156, 256, 0, stream>>>(Whh0, Wih1, Whh1, fcW, bih1, bhh1,
                                   Wp0, Wp1i, Wp1h, fcF, b1p);
  k_x0<<<dim3(128, 16), 256, 0, stream>>>(xcatT, Wih0, bih0, bhh0, x0F);
  k_lstm<<<256, 512, 0, stream>>>(x0F, Wp0, Wp1i, Wp1h, fcF, b1p, fcb,
                                  h0b, h1b, flags, (float*)d_out);
}